// Round 2
// baseline (444.128 us; speedup 1.0000x reference)
//
#include <hip/hip_runtime.h>

#define N_NODES 50000
#define N_EDGES 1600000
#define CAP 64            // bucket capacity per node; Poisson(32) tail @64 ~ 1e-7
#define OVF_CAP 8192

// Binned build parameters
#define BIN_SHIFT 7
#define BIN_NODES 128               // nodes per bin = 1<<BIN_SHIFT
#define NBINS 391                   // ceil(50000/128)
#define BIN_CAP 5120                // mean 4092, sigma ~64 -> 16 sigma headroom
#define EPB 4096                    // edges per k_part block

// Workspace element offsets (4-byte units). Peak ~77.4 MB.
#define O_CNTO   0         // int[50000]  out-degree
#define O_CNTI   50000     // int[50000]  in-degree (also bucket fill)
#define O_OVFN   100000    // int[1]      overflow count
#define O_OVF    100002    // int2[8192]  overflow (dst,src) pairs
#define O_BINC   116400    // int[391]    per-bin edge count (ends 116791 < 120000)
#define O_BUCKET 120000    // int[50000*64] src per slot
#define O_HB     3320000   // uint[3.2M]  bf16x2 h*norm_out
#define O_AGGB   6520000   // uint[3.2M]  bf16x2 agg rows (256 B/node)
#define O_WT     9720000   // uint[24576] bf16 W^T for Q,K,V: [3][128 n][64 k-pairs]
#define O_QB     9750000   // uint[3.2M]  bf16x2 Q rows (64 uints/node)
#define O_KV     12950000  // uint[6.4M]  interleaved bf16 K/V rows (512 B/node)
// pairs overlays hb/aggb: written by k_part, dead after k_bins, before k_hb/k_agg write
#define O_PAIRS  3320000   // int2[391*5120] = 16.0 MB, ends at float-ofs 7323840 < O_WT

typedef unsigned int uint;
typedef __attribute__((ext_vector_type(8))) short short8;
typedef __attribute__((ext_vector_type(4))) float floatx4;

union U16 { uint4 u; short8 s; };

__device__ __forceinline__ uint f2bf2(float a, float b) {
    uint ua = __float_as_uint(a); ua = (ua + 0x7fffu + ((ua >> 16) & 1u)) >> 16;
    uint ub = __float_as_uint(b); ub = (ub + 0x7fffu + ((ub >> 16) & 1u)) >> 16;
    return ua | (ub << 16);
}
__device__ __forceinline__ float bflo(uint u) { return __uint_as_float(u << 16); }
__device__ __forceinline__ float bfhi(uint u) { return __uint_as_float(u & 0xffff0000u); }

// Phase A: bin edges by dst>>7. LDS histogram -> chunked global reservation ->
// scatter (dst,src) pairs into per-bin arrays. cnt_out atomic rides along
// (fire-and-forget, no return dependency).
__global__ __launch_bounds__(256) void k_part(const int* __restrict__ src,
                                              const int* __restrict__ dst,
                                              int* cnt_out,
                                              int* bin_cnt,
                                              int2* __restrict__ pairs) {
    __shared__ int hist[NBINS];
    __shared__ int base[NBINS];
    const int t = threadIdx.x;
    const int e0 = blockIdx.x * EPB;

    for (int b = t; b < NBINS; b += 256) hist[b] = 0;
    __syncthreads();

    #pragma unroll
    for (int i = 0; i < EPB / 256; ++i) {
        int e = e0 + i * 256 + t;
        if (e < N_EDGES) {
            int d = dst[e];
            atomicAdd(&hist[d >> BIN_SHIFT], 1);
            atomicAdd(&cnt_out[src[e]], 1);
        }
    }
    __syncthreads();

    for (int b = t; b < NBINS; b += 256) {
        base[b] = atomicAdd(&bin_cnt[b], hist[b]);
        hist[b] = 0;                  // reuse as cursor
    }
    __syncthreads();

    #pragma unroll
    for (int i = 0; i < EPB / 256; ++i) {
        int e = e0 + i * 256 + t;
        if (e < N_EDGES) {
            int d = dst[e], s = src[e];   // L2/L3-hot reload (saves 32 VGPRs)
            int bin = d >> BIN_SHIFT;
            int idx = base[bin] + atomicAdd(&hist[bin], 1);
            if (idx < BIN_CAP)            // statistically impossible to trip
                pairs[(size_t)bin * BIN_CAP + idx] = make_int2(d, s);
        }
    }
}

// Phase B: one block per bin. Position assignment via LDS atomics; bucket
// writes confined to a 32 KB region -> L2 lines fill before eviction.
// Then: bitonic-sort each node's bucket by src id (L2-hot read-modify-write).
// Sorted buckets make all gather waves sweep hb/kv in the same ascending
// order -> cross-wave temporal clustering of same-row accesses -> L2 hits.
__global__ __launch_bounds__(256) void k_bins(const int* __restrict__ bin_cnt,
                                              const int2* __restrict__ pairs,
                                              int* __restrict__ cnt_in,
                                              int* __restrict__ bucket,
                                              int* ovf_n, int2* __restrict__ ovf) {
    __shared__ int lcnt[BIN_NODES];
    const int b = blockIdx.x;
    const int t = threadIdx.x;
    for (int i = t; i < BIN_NODES; i += 256) lcnt[i] = 0;
    __syncthreads();

    const int nb = min(bin_cnt[b], BIN_CAP);
    const int2* pp = pairs + (size_t)b * BIN_CAP;
    for (int i = t; i < nb; i += 256) {
        int2 p = pp[i];                        // p.x = dst, p.y = src
        int pos = atomicAdd(&lcnt[p.x & (BIN_NODES - 1)], 1);
        if (pos < CAP) {
            bucket[((size_t)p.x << 6) + pos] = p.y;
        } else {                               // statistically never; safety net
            int o = atomicAdd(ovf_n, 1);
            if (o < OVF_CAP) ovf[o] = p;
        }
    }
    __syncthreads();

    const int node0 = b << BIN_SHIFT;
    for (int i = t; i < BIN_NODES; i += 256) {
        int n = node0 + i;
        if (n < N_NODES) cnt_in[n] = lcnt[i];  // total count incl. overflow
    }
    __syncthreads();

    // Bitonic sort of each bucket row (64 lanes, 21 compare-exchange steps).
    const int wv = t >> 6, ln = t & 63;
    for (int q = wv; q < BIN_NODES; q += 4) {
        int n = node0 + q;
        if (n >= N_NODES) continue;
        int m = min(lcnt[q], CAP);
        if (m <= 1) continue;
        int* br = bucket + ((size_t)n << 6);
        int v = (ln < m) ? br[ln] : 0x7fffffff;   // sentinel sorts to the top
        #pragma unroll
        for (int k = 2; k <= 64; k <<= 1) {
            #pragma unroll
            for (int j = k >> 1; j > 0; j >>= 1) {
                int p = __shfl_xor(v, j);
                bool keepMin = (((ln & j) == 0) == ((ln & k) == 0));
                v = keepMin ? min(v, p) : max(v, p);
            }
        }
        if (ln < m) br[ln] = v;
    }
}

// W^T cast: wt[y][n][k2] = bf16x2(W_y[2k2][n], W_y[2k2+1][n])
__global__ __launch_bounds__(256) void k_wt(const float* __restrict__ WQ,
                                            const float* __restrict__ WK,
                                            const float* __restrict__ WV,
                                            uint* __restrict__ wt) {
    int idx = blockIdx.x * 256 + threadIdx.x;   // [0, 3*8192)
    if (idx < 3 * 8192) {
        int y = idx >> 13;
        int rem = idx & 8191;
        int k2 = rem >> 7;          // 0..63
        int n  = rem & 127;         // coalesced reads
        const float* W = (y == 0) ? WQ : (y == 1) ? WK : WV;
        float a = W[(2 * k2) * 128 + n];
        float b = W[(2 * k2 + 1) * 128 + n];
        wt[(y << 13) + (n << 6) + k2] = f2bf2(a, b);
    }
}

// hb[n][j] = bf16(h[n][j] * rsqrt(max(deg_out,1)))
__global__ __launch_bounds__(256) void k_hb(const float* __restrict__ h,
                                            const int* __restrict__ cnt_out,
                                            uint* __restrict__ hb) {
    int idx = blockIdx.x * 256 + threadIdx.x;   // [0, N*64)
    if (idx < N_NODES * 64) {
        int n = idx >> 6;
        float no = rsqrtf(fmaxf((float)cnt_out[n], 1.0f));
        float2 hv = *(const float2*)(h + ((size_t)idx << 1));
        hb[idx] = f2bf2(hv.x * no, hv.y * no);
    }
}

// aggb[n] = bf16( rsqrt(max(deg_in,1)) * sum_{slots of n} hb[s] ); unroll x8
__global__ __launch_bounds__(256) void k_agg(
    const int* __restrict__ cnt_in, const int* __restrict__ bucket,
    const int* __restrict__ ovf_n, const int2* __restrict__ ovf,
    const uint* __restrict__ hb, uint* __restrict__ aggb)
{
    int n = blockIdx.x * 4 + (threadIdx.x >> 6);
    int lane = threadIdx.x & 63;
    int cnt = cnt_in[n];
    int m = min(cnt, CAP);
    const int* b = bucket + ((size_t)n << 6);
    float ax = 0.f, ay = 0.f;
    int i = 0;
    for (; i + 8 <= m; i += 8) {
        int s[8]; uint u[8];
        #pragma unroll
        for (int j = 0; j < 8; ++j) s[j] = b[i + j];
        #pragma unroll
        for (int j = 0; j < 8; ++j) u[j] = hb[((size_t)s[j] << 6) + lane];
        #pragma unroll
        for (int j = 0; j < 8; ++j) { ax += bflo(u[j]); ay += bfhi(u[j]); }
    }
    for (; i < m; ++i) {
        int s = b[i];
        uint u = hb[((size_t)s << 6) + lane];
        ax += bflo(u);
        ay += bfhi(u);
    }
    if (cnt > CAP) {                       // statistically never; correctness net
        int on = min(*ovf_n, OVF_CAP);
        for (int j = 0; j < on; ++j) {
            int2 p = ovf[j];
            if (p.x == n) {
                uint u = hb[((size_t)p.y << 6) + lane];
                ax += bflo(u);
                ay += bfhi(u);
            }
        }
    }
    float ni = rsqrtf(fmaxf((float)cnt, 1.0f));
    aggb[((size_t)n << 6) + lane] = f2bf2(ax * ni, ay * ni);
}

// Fused QKV projection via bf16 MFMA. grid (391, 3): y=0 -> qb (bf16 rows),
// y=1 -> K half of interleaved kv, y=2 -> V half.
__global__ __launch_bounds__(256) void k_qkv(
    const uint* __restrict__ aggb, const uint* __restrict__ wt,
    const float* __restrict__ bQ, const float* __restrict__ bK,
    const float* __restrict__ bV,
    uint* __restrict__ qb, uint* __restrict__ kv)
{
    const int y = blockIdx.y;
    const int row0 = blockIdx.x * 128;
    const float* bias = (y == 0) ? bQ : (y == 1) ? bK : bV;

    __shared__ uint sA[128 * 68];   // A tile, row stride 68 uints

    const int t = threadIdx.x;
    for (int idx = t; idx < 128 * 16; idx += 256) {
        int r = idx >> 4, c4 = (idx & 15) << 2;
        int row = row0 + r;
        uint4 v = make_uint4(0u, 0u, 0u, 0u);
        if (row < N_NODES) v = *(const uint4*)(aggb + ((size_t)row << 6) + c4);
        *(uint4*)(&sA[r * 68 + c4]) = v;
    }
    __syncthreads();

    const int wave = t >> 6;
    const int lane = t & 63;
    const int mrow = lane & 15;     // m (A) / n (B) / col (C)
    const int kq   = lane >> 4;     // 0..3
    const int mbase = wave * 32;
    const uint* wty = wt + (y << 13);

    floatx4 acc[2][8];
    for (int a = 0; a < 2; ++a)
        for (int b = 0; b < 8; ++b)
            acc[a][b] = (floatx4){0.f, 0.f, 0.f, 0.f};

    for (int kc = 0; kc < 128; kc += 32) {
        int koff = (kc >> 1) + (kq << 2);    // uint offset within a row
        short8 afr[2], bfr[8];
        for (int mt = 0; mt < 2; ++mt) {
            U16 u; u.u = *(const uint4*)(&sA[(mbase + mt * 16 + mrow) * 68 + koff]);
            afr[mt] = u.s;
        }
        for (int nt = 0; nt < 8; ++nt) {
            U16 u; u.u = *(const uint4*)(wty + ((nt * 16 + mrow) << 6) + koff);
            bfr[nt] = u.s;
        }
        for (int mt = 0; mt < 2; ++mt)
            for (int nt = 0; nt < 8; ++nt)
                acc[mt][nt] = __builtin_amdgcn_mfma_f32_16x16x32_bf16(
                    afr[mt], bfr[nt], acc[mt][nt], 0, 0, 0);
    }

    // C/D: col = lane&15 (= mrow), row = kq*4 + reg. Pack pairs via shfl_xor(1).
    if (y == 0) {
        for (int mt = 0; mt < 2; ++mt) {
            int rbase = row0 + mbase + mt * 16 + kq * 4;
            for (int nt = 0; nt < 8; ++nt) {
                int c = nt * 16 + mrow;
                float bv = bias[c];
                for (int r = 0; r < 4; ++r) {
                    float v = fmaxf(acc[mt][nt][r] + bv, 0.f);
                    float pv = __shfl_xor(v, 1);
                    int row = rbase + r;
                    if (((lane & 1) == 0) && row < N_NODES)
                        qb[((size_t)row << 6) + (c >> 1)] = f2bf2(v, pv);
                }
            }
        }
    } else {
        const int vo = (y == 2) ? 1 : 0;
        for (int mt = 0; mt < 2; ++mt) {
            int rbase = row0 + mbase + mt * 16 + kq * 4;
            for (int nt = 0; nt < 8; ++nt) {
                int c = nt * 16 + mrow;    // even for even lanes
                float bv = bias[c];
                for (int r = 0; r < 4; ++r) {
                    float v = fmaxf(acc[mt][nt][r] + bv, 0.f);
                    float pv = __shfl_xor(v, 1);
                    int row = rbase + r;
                    if (((lane & 1) == 0) && row < N_NODES)
                        kv[((size_t)row << 7) + c + vo] = f2bf2(v, pv);
                }
            }
        }
    }
}

__device__ __forceinline__ void attn_step(uint2 kvp, float qx, float qy,
                                          float& ax, float& ay, float& zacc) {
    float p = bflo(kvp.x) * qx + bfhi(kvp.x) * qy;
    p += __shfl_xor(p, 1);
    p += __shfl_xor(p, 2);
    p += __shfl_xor(p, 4);
    float sc = __expf(fminf(fmaxf(p * 0.25f, -10.f), 10.f));
    ax += bflo(kvp.y) * sc;
    ay += bfhi(kvp.y) * sc;
    zacc += sc;
}

// Attention gather over interleaved KV from buckets; one wave per node; unroll x8.
// lane owns dim pair `lane` (head = lane>>3).
__global__ __launch_bounds__(256) void k_attn(
    const int* __restrict__ cnt_in, const int* __restrict__ bucket,
    const int* __restrict__ ovf_n, const int2* __restrict__ ovf,
    const uint* __restrict__ qb, const uint* __restrict__ kv,
    float* __restrict__ out)
{
    int n = blockIdx.x * 4 + (threadIdx.x >> 6);
    int lane = threadIdx.x & 63;
    int cnt = cnt_in[n];
    int m = min(cnt, CAP);
    const int* b = bucket + ((size_t)n << 6);

    uint qu = qb[((size_t)n << 6) + lane];
    float qx = bflo(qu), qy = bfhi(qu);
    float ax = 0.f, ay = 0.f, zacc = 0.f;

    int i = 0;
    for (; i + 8 <= m; i += 8) {
        int s[8]; uint2 p[8];
        #pragma unroll
        for (int j = 0; j < 8; ++j) s[j] = b[i + j];
        #pragma unroll
        for (int j = 0; j < 8; ++j)
            p[j] = *(const uint2*)(kv + ((size_t)s[j] << 7) + (lane << 1));
        #pragma unroll
        for (int j = 0; j < 8; ++j)
            attn_step(p[j], qx, qy, ax, ay, zacc);
    }
    for (; i < m; ++i) {
        int s = b[i];
        uint2 p = *(const uint2*)(kv + ((size_t)s << 7) + (lane << 1));
        attn_step(p, qx, qy, ax, ay, zacc);
    }
    if (cnt > CAP) {                       // statistically never; correctness net
        int on = min(*ovf_n, OVF_CAP);
        for (int j = 0; j < on; ++j) {
            int2 pr = ovf[j];
            if (pr.x == n) {
                uint2 p = *(const uint2*)(kv + ((size_t)pr.y << 7) + (lane << 1));
                attn_step(p, qx, qy, ax, ay, zacc);
            }
        }
    }

    float inv = 1.0f / (zacc + 1e-6f);
    float2 o; o.x = ax * inv; o.y = ay * inv;
    *(float2*)(out + ((size_t)n << 7) + (lane << 1)) = o;
}

extern "C" void kernel_launch(void* const* d_in, const int* in_sizes, int n_in,
                              void* d_out, int out_size, void* d_ws, size_t ws_size,
                              hipStream_t stream) {
    const float* h   = (const float*)d_in[0];
    const float* WQ  = (const float*)d_in[1];
    const float* bQ  = (const float*)d_in[2];
    const float* WK  = (const float*)d_in[3];
    const float* bK  = (const float*)d_in[4];
    const float* WV  = (const float*)d_in[5];
    const float* bV  = (const float*)d_in[6];
    const int*   src = (const int*)d_in[7];
    const int*   dst = (const int*)d_in[8];
    float* out = (float*)d_out;
    float* ws  = (float*)d_ws;
    int*   wsi = (int*)d_ws;

    int*   cnt_out = wsi + O_CNTO;
    int*   cnt_in  = wsi + O_CNTI;
    int*   ovf_n   = wsi + O_OVFN;
    int2*  ovf     = (int2*)(wsi + O_OVF);
    int*   bin_cnt = wsi + O_BINC;
    int*   bucket  = wsi + O_BUCKET;
    int2*  pairs   = (int2*)(wsi + O_PAIRS);
    uint*  hb      = (uint*)(ws + O_HB);
    uint*  aggb    = (uint*)(ws + O_AGGB);
    uint*  wt      = (uint*)(ws + O_WT);
    uint*  qb      = (uint*)(ws + O_QB);
    uint*  kv      = (uint*)(ws + O_KV);

    // zero cnt_out, cnt_in, ovf_n, (ovf), bin_cnt in one shot
    hipMemsetAsync(wsi, 0, (O_BINC + NBINS) * sizeof(int), stream);

    k_wt<<<(3 * 8192 + 255) / 256, 256, 0, stream>>>(WQ, WK, WV, wt);

    k_part<<<(N_EDGES + EPB - 1) / EPB, 256, 0, stream>>>(src, dst, cnt_out,
                                                          bin_cnt, pairs);
    k_bins<<<NBINS, 256, 0, stream>>>(bin_cnt, pairs, cnt_in, bucket, ovf_n, ovf);

    k_hb<<<(N_NODES * 64 + 255) / 256, 256, 0, stream>>>(h, cnt_out, hb);

    k_agg<<<N_NODES / 4, 256, 0, stream>>>(cnt_in, bucket, ovf_n, ovf, hb, aggb);

    dim3 g_qkv((N_NODES + 127) / 128, 3);
    k_qkv<<<g_qkv, 256, 0, stream>>>(aggb, wt, bQ, bK, bV, qb, kv);

    k_attn<<<N_NODES / 4, 256, 0, stream>>>(cnt_in, bucket, ovf_n, ovf,
                                            qb, kv, out);
}

// Round 3
// 412.059 us; speedup vs baseline: 1.0778x; 1.0778x over previous
//
#include <hip/hip_runtime.h>

#define N_NODES 50000
#define N_EDGES 1600000
#define CAP 64            // bucket capacity per node; Poisson(32) tail @64 ~ 1e-7
#define OVF_CAP 8192

// Binned build parameters
#define BIN_SHIFT 7
#define BIN_NODES 128               // nodes per bin = 1<<BIN_SHIFT
#define NBINS 391                   // ceil(50000/128)
#define BIN_CAP 5120                // mean 4092, sigma ~64 -> 16 sigma headroom
#define EPB 4096                    // edges per k_part block

// Workspace element offsets (4-byte units). Peak ~77.4 MB.
#define O_CNTO   0         // int[50000]  out-degree
#define O_CNTI   50000     // int[50000]  in-degree (also bucket fill)
#define O_OVFN   100000    // int[1]      overflow count
#define O_OVF    100002    // int2[8192]  overflow (dst,src) pairs
#define O_BINC   116400    // int[391]    per-bin edge count (ends 116791 < 120000)
#define O_BUCKET 120000    // int[50000*64] src per slot
#define O_HB     3320000   // uint[3.2M]  bf16x2 h*norm_out
#define O_AGGB   6520000   // uint[3.2M]  bf16x2 agg rows (256 B/node)
#define O_WT     9720000   // uint[24576] bf16 W^T for Q,K,V: [3][128 n][64 k-pairs]
#define O_QB     9750000   // uint[3.2M]  bf16x2 Q rows (64 uints/node)
#define O_KV     12950000  // uint[6.4M]  interleaved bf16 K/V rows (512 B/node)
// pairs overlays hb/aggb: written by k_part, dead after k_bins, before k_hb/k_agg write
#define O_PAIRS  3320000   // int2[391*5120] = 16.0 MB, ends at float-ofs 7323840 < O_WT

typedef unsigned int uint;
typedef __attribute__((ext_vector_type(8))) short short8;
typedef __attribute__((ext_vector_type(4))) float floatx4;

union U16 { uint4 u; short8 s; };

__device__ __forceinline__ uint f2bf2(float a, float b) {
    uint ua = __float_as_uint(a); ua = (ua + 0x7fffu + ((ua >> 16) & 1u)) >> 16;
    uint ub = __float_as_uint(b); ub = (ub + 0x7fffu + ((ub >> 16) & 1u)) >> 16;
    return ua | (ub << 16);
}
__device__ __forceinline__ float bflo(uint u) { return __uint_as_float(u << 16); }
__device__ __forceinline__ float bfhi(uint u) { return __uint_as_float(u & 0xffff0000u); }

// DPP cross-lane: VALU-only (no ds_bpermute, no lgkmcnt stalls).
// 0xB1 = quad_perm(1,0,3,2) = xor1; 0x4E = quad_perm(2,3,0,1) = xor2;
// 0x141 = row_half_mirror = xor7 within 8 (== xor4 once quads are uniform).
template<int CTRL>
__device__ __forceinline__ float dpp_add8(float x) {
    int t = __builtin_amdgcn_update_dpp(0, __float_as_int(x), CTRL, 0xF, 0xF, true);
    return x + __int_as_float(t);
}
__device__ __forceinline__ float dpp_xor1(float x) {
    int t = __builtin_amdgcn_update_dpp(0, __float_as_int(x), 0xB1, 0xF, 0xF, true);
    return __int_as_float(t);
}

// Phase A: bin edges by dst>>7. LDS histogram -> chunked global reservation ->
// scatter (dst,src) pairs into per-bin arrays. cnt_out atomic rides along
// (fire-and-forget, no return dependency).
__global__ __launch_bounds__(256) void k_part(const int* __restrict__ src,
                                              const int* __restrict__ dst,
                                              int* cnt_out,
                                              int* bin_cnt,
                                              int2* __restrict__ pairs) {
    __shared__ int hist[NBINS];
    __shared__ int base[NBINS];
    const int t = threadIdx.x;
    const int e0 = blockIdx.x * EPB;

    for (int b = t; b < NBINS; b += 256) hist[b] = 0;
    __syncthreads();

    #pragma unroll
    for (int i = 0; i < EPB / 256; ++i) {
        int e = e0 + i * 256 + t;
        if (e < N_EDGES) {
            int d = dst[e];
            atomicAdd(&hist[d >> BIN_SHIFT], 1);
            atomicAdd(&cnt_out[src[e]], 1);
        }
    }
    __syncthreads();

    for (int b = t; b < NBINS; b += 256) {
        base[b] = atomicAdd(&bin_cnt[b], hist[b]);
        hist[b] = 0;                  // reuse as cursor
    }
    __syncthreads();

    #pragma unroll
    for (int i = 0; i < EPB / 256; ++i) {
        int e = e0 + i * 256 + t;
        if (e < N_EDGES) {
            int d = dst[e], s = src[e];   // L2/L3-hot reload (saves 32 VGPRs)
            int bin = d >> BIN_SHIFT;
            int idx = base[bin] + atomicAdd(&hist[bin], 1);
            if (idx < BIN_CAP)            // statistically impossible to trip
                pairs[(size_t)bin * BIN_CAP + idx] = make_int2(d, s);
        }
    }
}

// Phase B: one block per bin. Position assignment via LDS atomics; bucket
// writes confined to a 32 KB region -> L2 lines fill before eviction.
__global__ __launch_bounds__(256) void k_bins(const int* __restrict__ bin_cnt,
                                              const int2* __restrict__ pairs,
                                              int* __restrict__ cnt_in,
                                              int* __restrict__ bucket,
                                              int* ovf_n, int2* __restrict__ ovf) {
    __shared__ int lcnt[BIN_NODES];
    const int b = blockIdx.x;
    const int t = threadIdx.x;
    for (int i = t; i < BIN_NODES; i += 256) lcnt[i] = 0;
    __syncthreads();

    const int nb = min(bin_cnt[b], BIN_CAP);
    const int2* pp = pairs + (size_t)b * BIN_CAP;
    for (int i = t; i < nb; i += 256) {
        int2 p = pp[i];                        // p.x = dst, p.y = src
        int pos = atomicAdd(&lcnt[p.x & (BIN_NODES - 1)], 1);
        if (pos < CAP) {
            bucket[((size_t)p.x << 6) + pos] = p.y;
        } else {                               // statistically never; safety net
            int o = atomicAdd(ovf_n, 1);
            if (o < OVF_CAP) ovf[o] = p;
        }
    }
    __syncthreads();

    const int node0 = b << BIN_SHIFT;
    for (int i = t; i < BIN_NODES; i += 256) {
        int n = node0 + i;
        if (n < N_NODES) cnt_in[n] = lcnt[i];  // total count incl. overflow
    }
}

// W^T cast: wt[y][n][k2] = bf16x2(W_y[2k2][n], W_y[2k2+1][n])
__global__ __launch_bounds__(256) void k_wt(const float* __restrict__ WQ,
                                            const float* __restrict__ WK,
                                            const float* __restrict__ WV,
                                            uint* __restrict__ wt) {
    int idx = blockIdx.x * 256 + threadIdx.x;   // [0, 3*8192)
    if (idx < 3 * 8192) {
        int y = idx >> 13;
        int rem = idx & 8191;
        int k2 = rem >> 7;          // 0..63
        int n  = rem & 127;         // coalesced reads
        const float* W = (y == 0) ? WQ : (y == 1) ? WK : WV;
        float a = W[(2 * k2) * 128 + n];
        float b = W[(2 * k2 + 1) * 128 + n];
        wt[(y << 13) + (n << 6) + k2] = f2bf2(a, b);
    }
}

// hb[n][j] = bf16(h[n][j] * rsqrt(max(deg_out,1)))
__global__ __launch_bounds__(256) void k_hb(const float* __restrict__ h,
                                            const int* __restrict__ cnt_out,
                                            uint* __restrict__ hb) {
    int idx = blockIdx.x * 256 + threadIdx.x;   // [0, N*64)
    if (idx < N_NODES * 64) {
        int n = idx >> 6;
        float no = rsqrtf(fmaxf((float)cnt_out[n], 1.0f));
        float2 hv = *(const float2*)(h + ((size_t)idx << 1));
        hb[idx] = f2bf2(hv.x * no, hv.y * no);
    }
}

// aggb[n] = bf16( rsqrt(max(deg_in,1)) * sum_{slots of n} hb[s] ); unroll x8
__global__ __launch_bounds__(256) void k_agg(
    const int* __restrict__ cnt_in, const int* __restrict__ bucket,
    const int* __restrict__ ovf_n, const int2* __restrict__ ovf,
    const uint* __restrict__ hb, uint* __restrict__ aggb)
{
    int n = blockIdx.x * 4 + (threadIdx.x >> 6);
    int lane = threadIdx.x & 63;
    int cnt = cnt_in[n];
    int m = min(cnt, CAP);
    const int* b = bucket + ((size_t)n << 6);
    float ax = 0.f, ay = 0.f;
    int i = 0;
    for (; i + 8 <= m; i += 8) {
        int4 sv0 = *(const int4*)(b + i);
        int4 sv1 = *(const int4*)(b + i + 4);
        int s[8] = {sv0.x, sv0.y, sv0.z, sv0.w, sv1.x, sv1.y, sv1.z, sv1.w};
        uint u[8];
        #pragma unroll
        for (int j = 0; j < 8; ++j) u[j] = hb[((uint)s[j] << 6) + (uint)lane];
        #pragma unroll
        for (int j = 0; j < 8; ++j) { ax += bflo(u[j]); ay += bfhi(u[j]); }
    }
    for (; i < m; ++i) {
        int s = b[i];
        uint u = hb[((uint)s << 6) + (uint)lane];
        ax += bflo(u);
        ay += bfhi(u);
    }
    if (cnt > CAP) {                       // statistically never; correctness net
        int on = min(*ovf_n, OVF_CAP);
        for (int j = 0; j < on; ++j) {
            int2 p = ovf[j];
            if (p.x == n) {
                uint u = hb[((uint)p.y << 6) + (uint)lane];
                ax += bflo(u);
                ay += bfhi(u);
            }
        }
    }
    float ni = rsqrtf(fmaxf((float)cnt, 1.0f));
    aggb[((size_t)n << 6) + lane] = f2bf2(ax * ni, ay * ni);
}

// Fused QKV projection via bf16 MFMA. grid (391, 3): y=0 -> qb (bf16 rows),
// y=1 -> K half of interleaved kv, y=2 -> V half.
__global__ __launch_bounds__(256) void k_qkv(
    const uint* __restrict__ aggb, const uint* __restrict__ wt,
    const float* __restrict__ bQ, const float* __restrict__ bK,
    const float* __restrict__ bV,
    uint* __restrict__ qb, uint* __restrict__ kv)
{
    const int y = blockIdx.y;
    const int row0 = blockIdx.x * 128;
    const float* bias = (y == 0) ? bQ : (y == 1) ? bK : bV;

    __shared__ uint sA[128 * 68];   // A tile, row stride 68 uints

    const int t = threadIdx.x;
    for (int idx = t; idx < 128 * 16; idx += 256) {
        int r = idx >> 4, c4 = (idx & 15) << 2;
        int row = row0 + r;
        uint4 v = make_uint4(0u, 0u, 0u, 0u);
        if (row < N_NODES) v = *(const uint4*)(aggb + ((size_t)row << 6) + c4);
        *(uint4*)(&sA[r * 68 + c4]) = v;
    }
    __syncthreads();

    const int wave = t >> 6;
    const int lane = t & 63;
    const int mrow = lane & 15;     // m (A) / n (B) / col (C)
    const int kq   = lane >> 4;     // 0..3
    const int mbase = wave * 32;
    const uint* wty = wt + (y << 13);

    floatx4 acc[2][8];
    for (int a = 0; a < 2; ++a)
        for (int b = 0; b < 8; ++b)
            acc[a][b] = (floatx4){0.f, 0.f, 0.f, 0.f};

    for (int kc = 0; kc < 128; kc += 32) {
        int koff = (kc >> 1) + (kq << 2);    // uint offset within a row
        short8 afr[2], bfr[8];
        for (int mt = 0; mt < 2; ++mt) {
            U16 u; u.u = *(const uint4*)(&sA[(mbase + mt * 16 + mrow) * 68 + koff]);
            afr[mt] = u.s;
        }
        for (int nt = 0; nt < 8; ++nt) {
            U16 u; u.u = *(const uint4*)(wty + ((nt * 16 + mrow) << 6) + koff);
            bfr[nt] = u.s;
        }
        for (int mt = 0; mt < 2; ++mt)
            for (int nt = 0; nt < 8; ++nt)
                acc[mt][nt] = __builtin_amdgcn_mfma_f32_16x16x32_bf16(
                    afr[mt], bfr[nt], acc[mt][nt], 0, 0, 0);
    }

    // C/D: col = lane&15 (= mrow), row = kq*4 + reg. Pack pairs via DPP xor1.
    if (y == 0) {
        for (int mt = 0; mt < 2; ++mt) {
            int rbase = row0 + mbase + mt * 16 + kq * 4;
            for (int nt = 0; nt < 8; ++nt) {
                int c = nt * 16 + mrow;
                float bv = bias[c];
                for (int r = 0; r < 4; ++r) {
                    float v = fmaxf(acc[mt][nt][r] + bv, 0.f);
                    float pv = dpp_xor1(v);
                    int row = rbase + r;
                    if (((lane & 1) == 0) && row < N_NODES)
                        qb[((size_t)row << 6) + (c >> 1)] = f2bf2(v, pv);
                }
            }
        }
    } else {
        const int vo = (y == 2) ? 1 : 0;
        for (int mt = 0; mt < 2; ++mt) {
            int rbase = row0 + mbase + mt * 16 + kq * 4;
            for (int nt = 0; nt < 8; ++nt) {
                int c = nt * 16 + mrow;    // even for even lanes
                float bv = bias[c];
                for (int r = 0; r < 4; ++r) {
                    float v = fmaxf(acc[mt][nt][r] + bv, 0.f);
                    float pv = dpp_xor1(v);
                    int row = rbase + r;
                    if (((lane & 1) == 0) && row < N_NODES)
                        kv[((size_t)row << 7) + c + vo] = f2bf2(v, pv);
                }
            }
        }
    }
}

// score path: p-scale folded with log2(e); clamp at +/-10*log2(e); raw v_exp_f32.
#define SC_MUL 0.36067376022243085f   // 0.25 * log2(e)
#define SC_CLP 14.426950408889634f    // 10.0 * log2(e)

__device__ __forceinline__ void attn_step(uint2 kvp, float qx, float qy,
                                          float& ax, float& ay, float& zacc) {
    float p = bflo(kvp.x) * qx + bfhi(kvp.x) * qy;
    p = dpp_add8<0xB1>(p);    // + xor1
    p = dpp_add8<0x4E>(p);    // + xor2
    p = dpp_add8<0x141>(p);   // + xor7 (quad-uniform => == xor4)
    float tt = fminf(fmaxf(p * SC_MUL, -SC_CLP), SC_CLP);
    float sc;
    asm("v_exp_f32 %0, %1" : "=v"(sc) : "v"(tt));   // D = 2^S0
    ax += bflo(kvp.y) * sc;
    ay += bfhi(kvp.y) * sc;
    zacc += sc;
}

// Attention gather over interleaved KV from buckets; one wave per node; unroll x8.
// lane owns dim pair `lane` (head = lane>>3).
__global__ __launch_bounds__(256) void k_attn(
    const int* __restrict__ cnt_in, const int* __restrict__ bucket,
    const int* __restrict__ ovf_n, const int2* __restrict__ ovf,
    const uint* __restrict__ qb, const uint* __restrict__ kv,
    float* __restrict__ out)
{
    int n = blockIdx.x * 4 + (threadIdx.x >> 6);
    int lane = threadIdx.x & 63;
    int cnt = cnt_in[n];
    int m = min(cnt, CAP);
    const int* b = bucket + ((size_t)n << 6);

    uint qu = qb[((size_t)n << 6) + lane];
    float qx = bflo(qu), qy = bfhi(qu);
    float ax = 0.f, ay = 0.f, zacc = 0.f;
    const uint loff = (uint)(lane << 1);

    int i = 0;
    for (; i + 8 <= m; i += 8) {
        int4 sv0 = *(const int4*)(b + i);
        int4 sv1 = *(const int4*)(b + i + 4);
        int s[8] = {sv0.x, sv0.y, sv0.z, sv0.w, sv1.x, sv1.y, sv1.z, sv1.w};
        uint2 p[8];
        #pragma unroll
        for (int j = 0; j < 8; ++j)
            p[j] = *(const uint2*)(kv + (((uint)s[j] << 7) + loff));
        #pragma unroll
        for (int j = 0; j < 8; ++j)
            attn_step(p[j], qx, qy, ax, ay, zacc);
    }
    for (; i < m; ++i) {
        int s = b[i];
        uint2 p = *(const uint2*)(kv + (((uint)s << 7) + loff));
        attn_step(p, qx, qy, ax, ay, zacc);
    }
    if (cnt > CAP) {                       // statistically never; correctness net
        int on = min(*ovf_n, OVF_CAP);
        for (int j = 0; j < on; ++j) {
            int2 pr = ovf[j];
            if (pr.x == n) {
                uint2 p = *(const uint2*)(kv + (((uint)pr.y << 7) + loff));
                attn_step(p, qx, qy, ax, ay, zacc);
            }
        }
    }

    float inv = 1.0f / (zacc + 1e-6f);
    float2 o; o.x = ax * inv; o.y = ay * inv;
    *(float2*)(out + ((size_t)n << 7) + (lane << 1)) = o;
}

extern "C" void kernel_launch(void* const* d_in, const int* in_sizes, int n_in,
                              void* d_out, int out_size, void* d_ws, size_t ws_size,
                              hipStream_t stream) {
    const float* h   = (const float*)d_in[0];
    const float* WQ  = (const float*)d_in[1];
    const float* bQ  = (const float*)d_in[2];
    const float* WK  = (const float*)d_in[3];
    const float* bK  = (const float*)d_in[4];
    const float* WV  = (const float*)d_in[5];
    const float* bV  = (const float*)d_in[6];
    const int*   src = (const int*)d_in[7];
    const int*   dst = (const int*)d_in[8];
    float* out = (float*)d_out;
    float* ws  = (float*)d_ws;
    int*   wsi = (int*)d_ws;

    int*   cnt_out = wsi + O_CNTO;
    int*   cnt_in  = wsi + O_CNTI;
    int*   ovf_n   = wsi + O_OVFN;
    int2*  ovf     = (int2*)(wsi + O_OVF);
    int*   bin_cnt = wsi + O_BINC;
    int*   bucket  = wsi + O_BUCKET;
    int2*  pairs   = (int2*)(wsi + O_PAIRS);
    uint*  hb      = (uint*)(ws + O_HB);
    uint*  aggb    = (uint*)(ws + O_AGGB);
    uint*  wt      = (uint*)(ws + O_WT);
    uint*  qb      = (uint*)(ws + O_QB);
    uint*  kv      = (uint*)(ws + O_KV);

    // zero cnt_out, cnt_in, ovf_n, (ovf), bin_cnt in one shot
    hipMemsetAsync(wsi, 0, (O_BINC + NBINS) * sizeof(int), stream);

    k_wt<<<(3 * 8192 + 255) / 256, 256, 0, stream>>>(WQ, WK, WV, wt);

    k_part<<<(N_EDGES + EPB - 1) / EPB, 256, 0, stream>>>(src, dst, cnt_out,
                                                          bin_cnt, pairs);
    k_bins<<<NBINS, 256, 0, stream>>>(bin_cnt, pairs, cnt_in, bucket, ovf_n, ovf);

    k_hb<<<(N_NODES * 64 + 255) / 256, 256, 0, stream>>>(h, cnt_out, hb);

    k_agg<<<N_NODES / 4, 256, 0, stream>>>(cnt_in, bucket, ovf_n, ovf, hb, aggb);

    dim3 g_qkv((N_NODES + 127) / 128, 3);
    k_qkv<<<g_qkv, 256, 0, stream>>>(aggb, wt, bQ, bK, bV, qb, kv);

    k_attn<<<N_NODES / 4, 256, 0, stream>>>(cnt_in, bucket, ovf_n, ovf,
                                            qb, kv, out);
}

// Round 4
// 402.394 us; speedup vs baseline: 1.1037x; 1.0240x over previous
//
#include <hip/hip_runtime.h>

#define N_NODES 50000
#define N_EDGES 1600000
#define CAP 64            // bucket capacity per node; Poisson(32) tail @64 ~ 1e-7
#define OVF_CAP 8192

// Binned build parameters
#define BIN_SHIFT 7
#define BIN_NODES 128               // nodes per bin = 1<<BIN_SHIFT
#define NBINS 391                   // ceil(50000/128)
#define BIN_CAP 5120                // mean 4092, sigma ~64 -> 16 sigma headroom
#define EPB 4096                    // edges per k_part block

// Workspace element offsets (4-byte units). Peak ~77.4 MB.
#define O_CNTO   0         // int[50000]  out-degree
#define O_CNTI   50000     // int[50000]  in-degree (also bucket fill)
#define O_OVFN   100000    // int[1]      overflow count
#define O_OVF    100002    // int2[8192]  overflow (dst,src) pairs
#define O_BINC   116400    // int[391]    per-bin edge count (ends 116791 < 120000)
#define O_BUCKET 120000    // int[50000*64] src per slot
#define O_HB     3320000   // uint[3.2M]  bf16x2 h*norm_out
#define O_AGGB   6520000   // uint[3.2M]  bf16x2 agg rows (256 B/node)
#define O_WT     9720000   // uint[24576] bf16 W^T for Q,K,V: [3][128 n][64 k-pairs]
#define O_QB     9750000   // uint[3.2M]  bf16x2 Q rows (64 uints/node)
#define O_KV     12950000  // uint[6.4M]  interleaved bf16 K/V rows (512 B/node)
// pairs overlays hb/aggb: written by k_part, dead after k_bins, before k_hb/k_agg write
#define O_PAIRS  3320000   // int2[391*5120] = 16.0 MB, ends at float-ofs 7323840 < O_WT

typedef unsigned int uint;
typedef __attribute__((ext_vector_type(8))) short short8;
typedef __attribute__((ext_vector_type(4))) float floatx4;

union U16 { uint4 u; short8 s; };

__device__ __forceinline__ uint f2bf2(float a, float b) {
    uint ua = __float_as_uint(a); ua = (ua + 0x7fffu + ((ua >> 16) & 1u)) >> 16;
    uint ub = __float_as_uint(b); ub = (ub + 0x7fffu + ((ub >> 16) & 1u)) >> 16;
    return ua | (ub << 16);
}
__device__ __forceinline__ float bflo(uint u) { return __uint_as_float(u << 16); }
__device__ __forceinline__ float bfhi(uint u) { return __uint_as_float(u & 0xffff0000u); }

// DPP cross-lane: VALU-only (no ds_bpermute, no lgkmcnt stalls).
// 0xB1 = quad_perm(1,0,3,2) = xor1; 0x4E = quad_perm(2,3,0,1) = xor2;
// 0x141 = row_half_mirror = xor7 within 8 (== xor4 once quads are uniform).
template<int CTRL>
__device__ __forceinline__ float dpp_add8(float x) {
    int t = __builtin_amdgcn_update_dpp(0, __float_as_int(x), CTRL, 0xF, 0xF, true);
    return x + __int_as_float(t);
}
__device__ __forceinline__ float dpp_xor1(float x) {
    int t = __builtin_amdgcn_update_dpp(0, __float_as_int(x), 0xB1, 0xF, 0xF, true);
    return __int_as_float(t);
}

// Phase A: bin edges by dst>>7. LDS histogram -> chunked global reservation ->
// scatter (dst,src) pairs into per-bin arrays. cnt_out atomic rides along
// (fire-and-forget, no return dependency).
__global__ __launch_bounds__(256) void k_part(const int* __restrict__ src,
                                              const int* __restrict__ dst,
                                              int* cnt_out,
                                              int* bin_cnt,
                                              int2* __restrict__ pairs) {
    __shared__ int hist[NBINS];
    __shared__ int base[NBINS];
    const int t = threadIdx.x;
    const int e0 = blockIdx.x * EPB;

    for (int b = t; b < NBINS; b += 256) hist[b] = 0;
    __syncthreads();

    #pragma unroll
    for (int i = 0; i < EPB / 256; ++i) {
        int e = e0 + i * 256 + t;
        if (e < N_EDGES) {
            int d = dst[e];
            atomicAdd(&hist[d >> BIN_SHIFT], 1);
            atomicAdd(&cnt_out[src[e]], 1);
        }
    }
    __syncthreads();

    for (int b = t; b < NBINS; b += 256) {
        base[b] = atomicAdd(&bin_cnt[b], hist[b]);
        hist[b] = 0;                  // reuse as cursor
    }
    __syncthreads();

    #pragma unroll
    for (int i = 0; i < EPB / 256; ++i) {
        int e = e0 + i * 256 + t;
        if (e < N_EDGES) {
            int d = dst[e], s = src[e];   // L2/L3-hot reload (saves 32 VGPRs)
            int bin = d >> BIN_SHIFT;
            int idx = base[bin] + atomicAdd(&hist[bin], 1);
            if (idx < BIN_CAP)            // statistically impossible to trip
                pairs[(size_t)bin * BIN_CAP + idx] = make_int2(d, s);
        }
    }
}

// Phase B: one block per bin. Position assignment via LDS atomics; bucket
// writes confined to a 32 KB region -> L2 lines fill before eviction.
__global__ __launch_bounds__(256) void k_bins(const int* __restrict__ bin_cnt,
                                              const int2* __restrict__ pairs,
                                              int* __restrict__ cnt_in,
                                              int* __restrict__ bucket,
                                              int* ovf_n, int2* __restrict__ ovf) {
    __shared__ int lcnt[BIN_NODES];
    const int b = blockIdx.x;
    const int t = threadIdx.x;
    for (int i = t; i < BIN_NODES; i += 256) lcnt[i] = 0;
    __syncthreads();

    const int nb = min(bin_cnt[b], BIN_CAP);
    const int2* pp = pairs + (size_t)b * BIN_CAP;
    for (int i = t; i < nb; i += 256) {
        int2 p = pp[i];                        // p.x = dst, p.y = src
        int pos = atomicAdd(&lcnt[p.x & (BIN_NODES - 1)], 1);
        if (pos < CAP) {
            bucket[((size_t)p.x << 6) + pos] = p.y;
        } else {                               // statistically never; safety net
            int o = atomicAdd(ovf_n, 1);
            if (o < OVF_CAP) ovf[o] = p;
        }
    }
    __syncthreads();

    const int node0 = b << BIN_SHIFT;
    for (int i = t; i < BIN_NODES; i += 256) {
        int n = node0 + i;
        if (n < N_NODES) cnt_in[n] = lcnt[i];  // total count incl. overflow
    }
}

// W^T cast: wt[y][n][k2] = bf16x2(W_y[2k2][n], W_y[2k2+1][n])
__global__ __launch_bounds__(256) void k_wt(const float* __restrict__ WQ,
                                            const float* __restrict__ WK,
                                            const float* __restrict__ WV,
                                            uint* __restrict__ wt) {
    int idx = blockIdx.x * 256 + threadIdx.x;   // [0, 3*8192)
    if (idx < 3 * 8192) {
        int y = idx >> 13;
        int rem = idx & 8191;
        int k2 = rem >> 7;          // 0..63
        int n  = rem & 127;         // coalesced reads
        const float* W = (y == 0) ? WQ : (y == 1) ? WK : WV;
        float a = W[(2 * k2) * 128 + n];
        float b = W[(2 * k2 + 1) * 128 + n];
        wt[(y << 13) + (n << 6) + k2] = f2bf2(a, b);
    }
}

// hb[n][j] = bf16(h[n][j] * rsqrt(max(deg_out,1)))
__global__ __launch_bounds__(256) void k_hb(const float* __restrict__ h,
                                            const int* __restrict__ cnt_out,
                                            uint* __restrict__ hb) {
    int idx = blockIdx.x * 256 + threadIdx.x;   // [0, N*64)
    if (idx < N_NODES * 64) {
        int n = idx >> 6;
        float no = rsqrtf(fmaxf((float)cnt_out[n], 1.0f));
        float2 hv = *(const float2*)(h + ((size_t)idx << 1));
        hb[idx] = f2bf2(hv.x * no, hv.y * no);
    }
}

// aggb[n] = bf16( rsqrt(max(deg_in,1)) * sum_{slots of n} hb[s] )
// Bucket row lives in-lane (b[lane]); batch indices via v_readlane (no memory
// dep); 16-wide double-buffered row loads -> compute overlaps fetch.
__global__ __launch_bounds__(256) void k_agg(
    const int* __restrict__ cnt_in, const int* __restrict__ bucket,
    const int* __restrict__ ovf_n, const int2* __restrict__ ovf,
    const uint* __restrict__ hb, uint* __restrict__ aggb)
{
    int n = blockIdx.x * 4 + (threadIdx.x >> 6);
    int lane = threadIdx.x & 63;
    int cnt = cnt_in[n];
    int m = min(cnt, CAP);
    const int* b = bucket + ((size_t)n << 6);
    int s_own = b[lane];                 // whole bucket row, one coalesced load
    float ax = 0.f, ay = 0.f;

    if (m > 0) {
        uint uA[16], uB[16];
        const int nb = (m + 15) >> 4;
        const int mm1 = m - 1;

#define AGLD(P, base) do { _Pragma("unroll")                                   \
        for (int j = 0; j < 16; ++j) {                                         \
            int sj = __builtin_amdgcn_readlane(s_own, min((base) + j, mm1));   \
            P[j] = hb[((uint)sj << 6) + (uint)lane];                           \
        } } while (0)
#define AGCMP(P, base) do { _Pragma("unroll")                                  \
        for (int j = 0; j < 16; ++j) {                                         \
            if ((base) + j < m) { ax += bflo(P[j]); ay += bfhi(P[j]); }        \
        } } while (0)

        AGLD(uA, 0);
        int t = 0;
        while (t + 1 < nb) {
            AGLD(uB, (t + 1) << 4);
            AGCMP(uA, t << 4);
            ++t;
            if (t + 1 < nb) {
                AGLD(uA, (t + 1) << 4);
                AGCMP(uB, t << 4);
                ++t;
            } else {
                AGCMP(uB, t << 4);
                ++t;
                break;
            }
        }
        if (t < nb) { AGCMP(uA, t << 4); }
#undef AGLD
#undef AGCMP
    }

    if (cnt > CAP) {                       // statistically never; correctness net
        int on = min(*ovf_n, OVF_CAP);
        for (int j = 0; j < on; ++j) {
            int2 p = ovf[j];
            if (p.x == n) {
                uint u = hb[((uint)p.y << 6) + (uint)lane];
                ax += bflo(u);
                ay += bfhi(u);
            }
        }
    }
    float ni = rsqrtf(fmaxf((float)cnt, 1.0f));
    aggb[((size_t)n << 6) + lane] = f2bf2(ax * ni, ay * ni);
}

// Fused QKV projection via bf16 MFMA. grid (391, 3): y=0 -> qb (bf16 rows),
// y=1 -> K half of interleaved kv, y=2 -> V half.
__global__ __launch_bounds__(256) void k_qkv(
    const uint* __restrict__ aggb, const uint* __restrict__ wt,
    const float* __restrict__ bQ, const float* __restrict__ bK,
    const float* __restrict__ bV,
    uint* __restrict__ qb, uint* __restrict__ kv)
{
    const int y = blockIdx.y;
    const int row0 = blockIdx.x * 128;
    const float* bias = (y == 0) ? bQ : (y == 1) ? bK : bV;

    __shared__ uint sA[128 * 68];   // A tile, row stride 68 uints

    const int t = threadIdx.x;
    for (int idx = t; idx < 128 * 16; idx += 256) {
        int r = idx >> 4, c4 = (idx & 15) << 2;
        int row = row0 + r;
        uint4 v = make_uint4(0u, 0u, 0u, 0u);
        if (row < N_NODES) v = *(const uint4*)(aggb + ((size_t)row << 6) + c4);
        *(uint4*)(&sA[r * 68 + c4]) = v;
    }
    __syncthreads();

    const int wave = t >> 6;
    const int lane = t & 63;
    const int mrow = lane & 15;     // m (A) / n (B) / col (C)
    const int kq   = lane >> 4;     // 0..3
    const int mbase = wave * 32;
    const uint* wty = wt + (y << 13);

    floatx4 acc[2][8];
    for (int a = 0; a < 2; ++a)
        for (int b = 0; b < 8; ++b)
            acc[a][b] = (floatx4){0.f, 0.f, 0.f, 0.f};

    for (int kc = 0; kc < 128; kc += 32) {
        int koff = (kc >> 1) + (kq << 2);    // uint offset within a row
        short8 afr[2], bfr[8];
        for (int mt = 0; mt < 2; ++mt) {
            U16 u; u.u = *(const uint4*)(&sA[(mbase + mt * 16 + mrow) * 68 + koff]);
            afr[mt] = u.s;
        }
        for (int nt = 0; nt < 8; ++nt) {
            U16 u; u.u = *(const uint4*)(wty + ((nt * 16 + mrow) << 6) + koff);
            bfr[nt] = u.s;
        }
        for (int mt = 0; mt < 2; ++mt)
            for (int nt = 0; nt < 8; ++nt)
                acc[mt][nt] = __builtin_amdgcn_mfma_f32_16x16x32_bf16(
                    afr[mt], bfr[nt], acc[mt][nt], 0, 0, 0);
    }

    // C/D: col = lane&15 (= mrow), row = kq*4 + reg. Pack pairs via DPP xor1.
    if (y == 0) {
        for (int mt = 0; mt < 2; ++mt) {
            int rbase = row0 + mbase + mt * 16 + kq * 4;
            for (int nt = 0; nt < 8; ++nt) {
                int c = nt * 16 + mrow;
                float bv = bias[c];
                for (int r = 0; r < 4; ++r) {
                    float v = fmaxf(acc[mt][nt][r] + bv, 0.f);
                    float pv = dpp_xor1(v);
                    int row = rbase + r;
                    if (((lane & 1) == 0) && row < N_NODES)
                        qb[((size_t)row << 6) + (c >> 1)] = f2bf2(v, pv);
                }
            }
        }
    } else {
        const int vo = (y == 2) ? 1 : 0;
        for (int mt = 0; mt < 2; ++mt) {
            int rbase = row0 + mbase + mt * 16 + kq * 4;
            for (int nt = 0; nt < 8; ++nt) {
                int c = nt * 16 + mrow;    // even for even lanes
                float bv = bias[c];
                for (int r = 0; r < 4; ++r) {
                    float v = fmaxf(acc[mt][nt][r] + bv, 0.f);
                    float pv = dpp_xor1(v);
                    int row = rbase + r;
                    if (((lane & 1) == 0) && row < N_NODES)
                        kv[((size_t)row << 7) + c + vo] = f2bf2(v, pv);
                }
            }
        }
    }
}

// score path: p-scale folded with log2(e); clamp at +/-10*log2(e); raw v_exp_f32.
#define SC_MUL 0.36067376022243085f   // 0.25 * log2(e)
#define SC_CLP 14.426950408889634f    // 10.0 * log2(e)

__device__ __forceinline__ void attn_step(uint2 kvp, float qx, float qy,
                                          float& ax, float& ay, float& zacc) {
    float p = bflo(kvp.x) * qx + bfhi(kvp.x) * qy;
    p = dpp_add8<0xB1>(p);    // + xor1
    p = dpp_add8<0x4E>(p);    // + xor2
    p = dpp_add8<0x141>(p);   // + xor7 (quad-uniform => == xor4)
    float tt = fminf(fmaxf(p * SC_MUL, -SC_CLP), SC_CLP);
    float sc;
    asm("v_exp_f32 %0, %1" : "=v"(sc) : "v"(tt));   // D = 2^S0
    ax += bflo(kvp.y) * sc;
    ay += bfhi(kvp.y) * sc;
    zacc += sc;
}

// Attention gather over interleaved KV. Bucket row in-lane + readlane indices;
// 8-wide double-buffered row loads (pA/pB, static indexing) -> the kv fetch of
// batch t+1 flies while batch t computes; no vmcnt(0) drain in the loop.
__global__ __launch_bounds__(256) void k_attn(
    const int* __restrict__ cnt_in, const int* __restrict__ bucket,
    const int* __restrict__ ovf_n, const int2* __restrict__ ovf,
    const uint* __restrict__ qb, const uint* __restrict__ kv,
    float* __restrict__ out)
{
    int n = blockIdx.x * 4 + (threadIdx.x >> 6);
    int lane = threadIdx.x & 63;
    int cnt = cnt_in[n];
    int m = min(cnt, CAP);
    const int* b = bucket + ((size_t)n << 6);
    int s_own = b[lane];                 // whole bucket row, one coalesced load

    uint qu = qb[((size_t)n << 6) + lane];
    float qx = bflo(qu), qy = bfhi(qu);
    float ax = 0.f, ay = 0.f, zacc = 0.f;
    const uint loff = (uint)(lane << 1);

    if (m > 0) {
        uint2 pA[8], pB[8];
        const int nb = (m + 7) >> 3;
        const int mm1 = m - 1;

#define KVLD(P, base) do { _Pragma("unroll")                                   \
        for (int j = 0; j < 8; ++j) {                                          \
            int sj = __builtin_amdgcn_readlane(s_own, min((base) + j, mm1));   \
            P[j] = *(const uint2*)(kv + (((uint)sj << 7) + loff));             \
        } } while (0)
#define KVCMP(P, base) do { _Pragma("unroll")                                  \
        for (int j = 0; j < 8; ++j) {                                          \
            if ((base) + j < m) attn_step(P[j], qx, qy, ax, ay, zacc);         \
        } } while (0)

        KVLD(pA, 0);
        int t = 0;
        while (t + 1 < nb) {
            KVLD(pB, (t + 1) << 3);
            KVCMP(pA, t << 3);
            ++t;
            if (t + 1 < nb) {
                KVLD(pA, (t + 1) << 3);
                KVCMP(pB, t << 3);
                ++t;
            } else {
                KVCMP(pB, t << 3);
                ++t;
                break;
            }
        }
        if (t < nb) { KVCMP(pA, t << 3); }
#undef KVLD
#undef KVCMP
    }

    if (cnt > CAP) {                       // statistically never; correctness net
        int on = min(*ovf_n, OVF_CAP);
        for (int j = 0; j < on; ++j) {
            int2 pr = ovf[j];
            if (pr.x == n) {
                uint2 p = *(const uint2*)(kv + (((uint)pr.y << 7) + loff));
                attn_step(p, qx, qy, ax, ay, zacc);
            }
        }
    }

    float inv = 1.0f / (zacc + 1e-6f);
    float2 o; o.x = ax * inv; o.y = ay * inv;
    *(float2*)(out + ((size_t)n << 7) + (lane << 1)) = o;
}

extern "C" void kernel_launch(void* const* d_in, const int* in_sizes, int n_in,
                              void* d_out, int out_size, void* d_ws, size_t ws_size,
                              hipStream_t stream) {
    const float* h   = (const float*)d_in[0];
    const float* WQ  = (const float*)d_in[1];
    const float* bQ  = (const float*)d_in[2];
    const float* WK  = (const float*)d_in[3];
    const float* bK  = (const float*)d_in[4];
    const float* WV  = (const float*)d_in[5];
    const float* bV  = (const float*)d_in[6];
    const int*   src = (const int*)d_in[7];
    const int*   dst = (const int*)d_in[8];
    float* out = (float*)d_out;
    float* ws  = (float*)d_ws;
    int*   wsi = (int*)d_ws;

    int*   cnt_out = wsi + O_CNTO;
    int*   cnt_in  = wsi + O_CNTI;
    int*   ovf_n   = wsi + O_OVFN;
    int2*  ovf     = (int2*)(wsi + O_OVF);
    int*   bin_cnt = wsi + O_BINC;
    int*   bucket  = wsi + O_BUCKET;
    int2*  pairs   = (int2*)(wsi + O_PAIRS);
    uint*  hb      = (uint*)(ws + O_HB);
    uint*  aggb    = (uint*)(ws + O_AGGB);
    uint*  wt      = (uint*)(ws + O_WT);
    uint*  qb      = (uint*)(ws + O_QB);
    uint*  kv      = (uint*)(ws + O_KV);

    // zero cnt_out, cnt_in, ovf_n, (ovf), bin_cnt in one shot
    hipMemsetAsync(wsi, 0, (O_BINC + NBINS) * sizeof(int), stream);

    k_wt<<<(3 * 8192 + 255) / 256, 256, 0, stream>>>(WQ, WK, WV, wt);

    k_part<<<(N_EDGES + EPB - 1) / EPB, 256, 0, stream>>>(src, dst, cnt_out,
                                                          bin_cnt, pairs);
    k_bins<<<NBINS, 256, 0, stream>>>(bin_cnt, pairs, cnt_in, bucket, ovf_n, ovf);

    k_hb<<<(N_NODES * 64 + 255) / 256, 256, 0, stream>>>(h, cnt_out, hb);

    k_agg<<<N_NODES / 4, 256, 0, stream>>>(cnt_in, bucket, ovf_n, ovf, hb, aggb);

    dim3 g_qkv((N_NODES + 127) / 128, 3);
    k_qkv<<<g_qkv, 256, 0, stream>>>(aggb, wt, bQ, bK, bV, qb, kv);

    k_attn<<<N_NODES / 4, 256, 0, stream>>>(cnt_in, bucket, ovf_n, ovf,
                                            qb, kv, out);
}